// Round 1
// baseline (1485.630 us; speedup 1.0000x reference)
//
#include <hip/hip_runtime.h>

#define IN_DIM 128
#define OUT_DIM 128

// ---------------- Projection: proj = relu(h @ W^T) ----------------
// A = h [M x 128] row-major, B = W [128 x 128] row-major (proj[m][n] = sum_k A[m][k]*B[n][k])
#define BM 64
#define BN 64
#define BK 16
#define LDS_PAD 68   // 68*4 = 272 bytes, 16B-aligned rows; breaks staging bank conflicts

__global__ __launch_bounds__(256) void proj_relu_kernel(const float* __restrict__ h,
                                                        const float* __restrict__ W,
                                                        float* __restrict__ proj,
                                                        int M) {
    __shared__ float As[BK][LDS_PAD];
    __shared__ float Bs[BK][LDS_PAD];

    const int t = threadIdx.x;
    const int block_m = blockIdx.x * BM;
    const int block_n = blockIdx.y * BN;
    const int tx = t & 15;        // 0..15  -> column group (4 cols)
    const int ty = t >> 4;        // 0..15  -> row group (4 rows)

    // staging: each thread loads one float4 (16 k-contiguous bytes) of A and B
    const int sm = t >> 2;        // 0..63 row within tile
    const int sc = t & 3;         // which float4 chunk of the BK=16 k's

    float acc[4][4] = {};

    for (int k0 = 0; k0 < IN_DIM; k0 += BK) {
        // --- stage A (h rows), transpose to k-major ---
        const int gm = block_m + sm;
        float4 av = make_float4(0.f, 0.f, 0.f, 0.f);
        if (gm < M) av = *(const float4*)&h[(long)gm * IN_DIM + k0 + sc * 4];
        As[sc * 4 + 0][sm] = av.x;
        As[sc * 4 + 1][sm] = av.y;
        As[sc * 4 + 2][sm] = av.z;
        As[sc * 4 + 3][sm] = av.w;
        // --- stage B (W rows), always in-range (N=128) ---
        float4 bv = *(const float4*)&W[(long)(block_n + sm) * IN_DIM + k0 + sc * 4];
        Bs[sc * 4 + 0][sm] = bv.x;
        Bs[sc * 4 + 1][sm] = bv.y;
        Bs[sc * 4 + 2][sm] = bv.z;
        Bs[sc * 4 + 3][sm] = bv.w;
        __syncthreads();

#pragma unroll
        for (int kk = 0; kk < BK; kk++) {
            float4 a = *(const float4*)&As[kk][ty * 4];
            float4 b = *(const float4*)&Bs[kk][tx * 4];
            float ar[4] = {a.x, a.y, a.z, a.w};
            float br[4] = {b.x, b.y, b.z, b.w};
#pragma unroll
            for (int i = 0; i < 4; i++)
#pragma unroll
                for (int j = 0; j < 4; j++)
                    acc[i][j] = fmaf(ar[i], br[j], acc[i][j]);
        }
        __syncthreads();
    }

    // epilogue: relu + store float4 per row
#pragma unroll
    for (int i = 0; i < 4; i++) {
        const int row = block_m + ty * 4 + i;
        if (row < M) {
            float4 v;
            v.x = fmaxf(acc[i][0], 0.f);
            v.y = fmaxf(acc[i][1], 0.f);
            v.z = fmaxf(acc[i][2], 0.f);
            v.w = fmaxf(acc[i][3], 0.f);
            *(float4*)&proj[(long)row * OUT_DIM + block_n + tx * 4] = v;
        }
    }
}

// ---------------- Scatter: out[dst[e]] += proj[src[e]] ----------------
// 32 threads per edge, one float4 each. out must be pre-zeroed.
__global__ __launch_bounds__(256) void scatter_kernel(const float* __restrict__ proj,
                                                      const int* __restrict__ src,
                                                      const int* __restrict__ dst,
                                                      float* __restrict__ out,
                                                      int E) {
    const long gid = (long)blockIdx.x * blockDim.x + threadIdx.x;
    const long e = gid >> 5;
    if (e >= E) return;
    const int l = (int)(gid & 31);

    const int s = src[e];
    const int d = dst[e];

    float4 v = *(const float4*)&proj[(long)s * OUT_DIM + l * 4];
    float* o = &out[(long)d * OUT_DIM + l * 4];
    atomicAdd(o + 0, v.x);
    atomicAdd(o + 1, v.y);
    atomicAdd(o + 2, v.z);
    atomicAdd(o + 3, v.w);
}

extern "C" void kernel_launch(void* const* d_in, const int* in_sizes, int n_in,
                              void* d_out, int out_size, void* d_ws, size_t ws_size,
                              hipStream_t stream) {
    const float* h   = (const float*)d_in[0];
    const float* W   = (const float*)d_in[1];
    const int*   src = (const int*)d_in[2];
    const int*   dst = (const int*)d_in[3];
    float* out = (float*)d_out;

    const int M = in_sizes[0] / IN_DIM;   // 100000 nodes
    const int E = in_sizes[2];            // 800000 edges

    float* proj = (float*)d_ws;           // M * 128 floats = 51.2 MB

    // 1) projection + relu
    dim3 grid_p((M + BM - 1) / BM, OUT_DIM / BN);
    proj_relu_kernel<<<grid_p, 256, 0, stream>>>(h, W, proj, M);

    // 2) zero the accumulator output
    hipMemsetAsync(d_out, 0, (size_t)out_size * sizeof(float), stream);

    // 3) atomic scatter over edges
    const long total = (long)E * 32;
    const int blocks = (int)((total + 255) / 256);
    scatter_kernel<<<blocks, 256, 0, stream>>>(proj, src, dst, out, E);
}

// Round 2
// 289.164 us; speedup vs baseline: 5.1377x; 5.1377x over previous
//
#include <hip/hip_runtime.h>

#define IN_DIM 128
#define OUT_DIM 128

// ---------------- Projection: proj = relu(h @ W^T) ----------------
#define BM 64
#define BN 64
#define BK 16
#define LDS_PAD 68

__global__ __launch_bounds__(256) void proj_relu_kernel(const float* __restrict__ h,
                                                        const float* __restrict__ W,
                                                        float* __restrict__ proj,
                                                        int M) {
    __shared__ float As[BK][LDS_PAD];
    __shared__ float Bs[BK][LDS_PAD];

    const int t = threadIdx.x;
    const int block_m = blockIdx.x * BM;
    const int block_n = blockIdx.y * BN;
    const int tx = t & 15;
    const int ty = t >> 4;
    const int sm = t >> 2;
    const int sc = t & 3;

    float acc[4][4] = {};

    for (int k0 = 0; k0 < IN_DIM; k0 += BK) {
        const int gm = block_m + sm;
        float4 av = make_float4(0.f, 0.f, 0.f, 0.f);
        if (gm < M) av = *(const float4*)&h[(long)gm * IN_DIM + k0 + sc * 4];
        As[sc * 4 + 0][sm] = av.x;
        As[sc * 4 + 1][sm] = av.y;
        As[sc * 4 + 2][sm] = av.z;
        As[sc * 4 + 3][sm] = av.w;
        float4 bv = *(const float4*)&W[(long)(block_n + sm) * IN_DIM + k0 + sc * 4];
        Bs[sc * 4 + 0][sm] = bv.x;
        Bs[sc * 4 + 1][sm] = bv.y;
        Bs[sc * 4 + 2][sm] = bv.z;
        Bs[sc * 4 + 3][sm] = bv.w;
        __syncthreads();

#pragma unroll
        for (int kk = 0; kk < BK; kk++) {
            float4 a = *(const float4*)&As[kk][ty * 4];
            float4 b = *(const float4*)&Bs[kk][tx * 4];
            float ar[4] = {a.x, a.y, a.z, a.w};
            float br[4] = {b.x, b.y, b.z, b.w};
#pragma unroll
            for (int i = 0; i < 4; i++)
#pragma unroll
                for (int j = 0; j < 4; j++)
                    acc[i][j] = fmaf(ar[i], br[j], acc[i][j]);
        }
        __syncthreads();
    }

#pragma unroll
    for (int i = 0; i < 4; i++) {
        const int row = block_m + ty * 4 + i;
        if (row < M) {
            float4 v;
            v.x = fmaxf(acc[i][0], 0.f);
            v.y = fmaxf(acc[i][1], 0.f);
            v.z = fmaxf(acc[i][2], 0.f);
            v.w = fmaxf(acc[i][3], 0.f);
            *(float4*)&proj[(long)row * OUT_DIM + block_n + tx * 4] = v;
        }
    }
}

// ---------------- CSR build ----------------
__global__ __launch_bounds__(256) void hist_kernel(const int* __restrict__ dst,
                                                   int* __restrict__ counts, int E) {
    int e = blockIdx.x * 256 + threadIdx.x;
    if (e < E) atomicAdd(&counts[dst[e]], 1);
}

// exclusive scan, hierarchical: K1 per-block scan, K2 scan of block sums, K3 add
__global__ __launch_bounds__(1024) void scan1_kernel(const int* __restrict__ counts,
                                                     int* __restrict__ offsets,
                                                     int* __restrict__ bsums, int N) {
    __shared__ int s[1024];
    const int t = threadIdx.x;
    const int i = blockIdx.x * 1024 + t;
    const int v = (i < N) ? counts[i] : 0;
    s[t] = v;
    __syncthreads();
#pragma unroll
    for (int off = 1; off < 1024; off <<= 1) {
        int x = (t >= off) ? s[t - off] : 0;
        __syncthreads();
        s[t] += x;
        __syncthreads();
    }
    if (i < N) offsets[i] = s[t] - v;          // exclusive
    if (t == 1023) bsums[blockIdx.x] = s[t];   // block total
}

__global__ __launch_bounds__(128) void scan2_kernel(int* __restrict__ bsums, int nb) {
    __shared__ int s[128];
    const int t = threadIdx.x;
    const int v = (t < nb) ? bsums[t] : 0;
    s[t] = v;
    __syncthreads();
#pragma unroll
    for (int off = 1; off < 128; off <<= 1) {
        int x = (t >= off) ? s[t - off] : 0;
        __syncthreads();
        s[t] += x;
        __syncthreads();
    }
    if (t < nb) bsums[t] = s[t] - v;           // exclusive, in place
}

__global__ __launch_bounds__(256) void scan3_kernel(int* __restrict__ offsets,
                                                    const int* __restrict__ bsums, int N) {
    int i = blockIdx.x * 256 + threadIdx.x;
    if (i < N) offsets[i] += bsums[i >> 10];
}

// bucket edges: after this, offsets[d] = END of bucket d (start = end - counts[d])
__global__ __launch_bounds__(256) void bucket_kernel(const int* __restrict__ src,
                                                     const int* __restrict__ dst,
                                                     int* __restrict__ offsets,
                                                     int* __restrict__ edge_src, int E) {
    int e = blockIdx.x * 256 + threadIdx.x;
    if (e < E) {
        int pos = atomicAdd(&offsets[dst[e]], 1);
        edge_src[pos] = src[e];
    }
}

// ---------------- Gather: out[d] = sum over in-edges of proj[src] ----------------
// one wave (64 lanes) per node; each lane owns a float2 of the 128-dim row.
__global__ __launch_bounds__(256) void gather_kernel(const float* __restrict__ proj,
                                                     const int* __restrict__ edge_src,
                                                     const int* __restrict__ offsets,
                                                     const int* __restrict__ counts,
                                                     float* __restrict__ out, int N) {
    const int node = blockIdx.x * 4 + (threadIdx.x >> 6);
    const int lane = threadIdx.x & 63;
    if (node >= N) return;

    const int end = offsets[node];
    const int cnt = counts[node];
    const int beg = end - cnt;

    float2 acc = make_float2(0.f, 0.f);
    int e = beg;
    // unroll-by-2 with independent loads to hide gather latency
    for (; e + 1 < end; e += 2) {
        int s0 = edge_src[e];
        int s1 = edge_src[e + 1];
        float2 v0 = *(const float2*)&proj[(long)s0 * OUT_DIM + lane * 2];
        float2 v1 = *(const float2*)&proj[(long)s1 * OUT_DIM + lane * 2];
        acc.x += v0.x + v1.x;
        acc.y += v0.y + v1.y;
    }
    if (e < end) {
        int s0 = edge_src[e];
        float2 v0 = *(const float2*)&proj[(long)s0 * OUT_DIM + lane * 2];
        acc.x += v0.x;
        acc.y += v0.y;
    }
    *(float2*)&out[(long)node * OUT_DIM + lane * 2] = acc;
}

extern "C" void kernel_launch(void* const* d_in, const int* in_sizes, int n_in,
                              void* d_out, int out_size, void* d_ws, size_t ws_size,
                              hipStream_t stream) {
    const float* h   = (const float*)d_in[0];
    const float* W   = (const float*)d_in[1];
    const int*   src = (const int*)d_in[2];
    const int*   dst = (const int*)d_in[3];
    float* out = (float*)d_out;

    const int M = in_sizes[0] / IN_DIM;   // nodes
    const int E = in_sizes[2];            // edges

    // workspace layout
    char* ws = (char*)d_ws;
    float* proj    = (float*)ws;                          // M*128 floats
    size_t off     = (size_t)M * OUT_DIM * sizeof(float);
    int* counts    = (int*)(ws + off); off += (size_t)M * sizeof(int);
    int* offsets   = (int*)(ws + off); off += (size_t)M * sizeof(int);
    int* bsums     = (int*)(ws + off); off += 1024 * sizeof(int);
    int* edge_src  = (int*)(ws + off); off += (size_t)E * sizeof(int);

    // 1) projection + relu
    dim3 grid_p((M + BM - 1) / BM, OUT_DIM / BN);
    proj_relu_kernel<<<grid_p, 256, 0, stream>>>(h, W, proj, M);

    // 2) CSR build
    hipMemsetAsync(counts, 0, (size_t)M * sizeof(int), stream);
    hist_kernel<<<(E + 255) / 256, 256, 0, stream>>>(dst, counts, E);
    const int nb = (M + 1023) / 1024;     // 98 for M=100000 (must be <=128)
    scan1_kernel<<<nb, 1024, 0, stream>>>(counts, offsets, bsums, M);
    scan2_kernel<<<1, 128, 0, stream>>>(bsums, nb);
    scan3_kernel<<<(M + 255) / 256, 256, 0, stream>>>(offsets, bsums, M);
    bucket_kernel<<<(E + 255) / 256, 256, 0, stream>>>(src, dst, offsets, edge_src, E);

    // 3) pull-gather (writes every output element exactly once; no memset of d_out needed)
    gather_kernel<<<(M + 3) / 4, 256, 0, stream>>>(proj, edge_src, offsets, counts, out, M);
}

// Round 3
// 251.507 us; speedup vs baseline: 5.9069x; 1.1497x over previous
//
#include <hip/hip_runtime.h>

#define IN_DIM 128
#define OUT_DIM 128

typedef __attribute__((ext_vector_type(8))) short short8;
typedef __attribute__((ext_vector_type(4))) float floatx4;

__device__ __forceinline__ unsigned short f2bf(float x) {
    union { float f; unsigned int u; } a; a.f = x;
    unsigned int u = a.u;
    unsigned int r = (u + 0x7fffu + ((u >> 16) & 1u)) >> 16;   // RNE
    return (unsigned short)r;
}
__device__ __forceinline__ float bf_lo(unsigned int v) {
    union { unsigned int u; float f; } a; a.u = v << 16; return a.f;
}
__device__ __forceinline__ float bf_hi(unsigned int v) {
    union { unsigned int u; float f; } a; a.u = v & 0xffff0000u; return a.f;
}

// ---------------- Projection: projb = bf16(relu(h @ W^T)) via MFMA ----------------
// Block: 256 threads (4 waves), 64 rows of h per block, full N=128.
// LDS: A 64x(128+8) bf16, B 128x(128+8) bf16 (pad 8 -> 16B-aligned rows, 2-way-max bank aliasing)
#define APAD 136

__global__ __launch_bounds__(256) void proj_mfma_kernel(const float* __restrict__ h,
                                                        const float* __restrict__ W,
                                                        unsigned short* __restrict__ projb,
                                                        int M) {
    __shared__ unsigned short As[64][APAD];    // 17408 B
    __shared__ unsigned short Bs[128][APAD];   // 34816 B

    const int t = threadIdx.x;
    const int wave = t >> 6;
    const int lane = t & 63;
    const int block_m = blockIdx.x * 64;

    // ---- stage A: 64 rows x 128 f32 -> bf16 LDS. 2048 float4 chunks / 256 thr = 8 passes
#pragma unroll
    for (int p = 0; p < 8; p++) {
        int c = p * 256 + t;
        int row = c >> 5;          // 0..63
        int ch  = c & 31;          // float4 chunk within row
        int gm = block_m + row;
        float4 v = make_float4(0.f, 0.f, 0.f, 0.f);
        if (gm < M) v = *(const float4*)&h[(size_t)gm * IN_DIM + ch * 4];
        ushort4 b;
        b.x = f2bf(v.x); b.y = f2bf(v.y); b.z = f2bf(v.z); b.w = f2bf(v.w);
        *(ushort4*)&As[row][ch * 4] = b;
    }
    // ---- stage B: W is [n][k] row-major, 128x128 f32 -> bf16 LDS. 4096 chunks -> 16 passes
#pragma unroll
    for (int p = 0; p < 16; p++) {
        int c = p * 256 + t;
        int row = c >> 5;          // n: 0..127
        int ch  = c & 31;
        float4 v = *(const float4*)&W[(size_t)row * IN_DIM + ch * 4];
        ushort4 b;
        b.x = f2bf(v.x); b.y = f2bf(v.y); b.z = f2bf(v.z); b.w = f2bf(v.w);
        *(ushort4*)&Bs[row][ch * 4] = b;
    }
    __syncthreads();

    // ---- MFMA: wave handles m-tile rows [wave*16, wave*16+16)
    const int mrow = wave * 16 + (lane & 15);
    const int kq   = (lane >> 4) * 8;          // quad's k base within 32-chunk
    floatx4 acc[8] = {};

#pragma unroll
    for (int ks = 0; ks < 4; ks++) {
        short8 a = *(const short8*)&As[mrow][ks * 32 + kq];
#pragma unroll
        for (int nt = 0; nt < 8; nt++) {
            short8 b = *(const short8*)&Bs[nt * 16 + (lane & 15)][ks * 32 + kq];
            acc[nt] = __builtin_amdgcn_mfma_f32_16x16x32_bf16(a, b, acc[nt], 0, 0, 0);
        }
    }

    // ---- epilogue: relu + bf16 store. C/D: col=lane&15, row=(lane>>4)*4+reg
    const int rbase = block_m + wave * 16 + (lane >> 4) * 4;
    const int col   = lane & 15;
#pragma unroll
    for (int nt = 0; nt < 8; nt++) {
#pragma unroll
        for (int i = 0; i < 4; i++) {
            int row = rbase + i;
            if (row < M)
                projb[(size_t)row * OUT_DIM + nt * 16 + col] = f2bf(fmaxf(acc[nt][i], 0.f));
        }
    }
}

// ---------------- CSR build ----------------
__global__ __launch_bounds__(256) void hist_kernel(const int* __restrict__ dst,
                                                   int* __restrict__ counts, int E) {
    int e = blockIdx.x * 256 + threadIdx.x;
    if (e < E) atomicAdd(&counts[dst[e]], 1);
}

__global__ __launch_bounds__(1024) void scan1_kernel(const int* __restrict__ counts,
                                                     int* __restrict__ offsets,
                                                     int* __restrict__ bsums, int N) {
    __shared__ int wsum[16];
    const int t = threadIdx.x, lane = t & 63, w = t >> 6;
    const int i = blockIdx.x * 1024 + t;
    const int v = (i < N) ? counts[i] : 0;
    int x = v;
#pragma unroll
    for (int d = 1; d < 64; d <<= 1) { int y = __shfl_up(x, d, 64); if (lane >= d) x += y; }
    if (lane == 63) wsum[w] = x;
    __syncthreads();
    if (t < 16) {
        int s = wsum[t];
        int xs = s;
#pragma unroll
        for (int d = 1; d < 16; d <<= 1) { int y = __shfl_up(xs, d, 64); if (t >= d) xs += y; }
        wsum[t] = xs - s;                       // exclusive wave prefix
        if (t == 15) bsums[blockIdx.x] = xs;    // block total
    }
    __syncthreads();
    if (i < N) offsets[i] = x - v + wsum[w];
}

__global__ __launch_bounds__(128) void scan2_kernel(int* __restrict__ bsums, int nb) {
    __shared__ int wsum[2];
    const int t = threadIdx.x, lane = t & 63, w = t >> 6;
    const int v = (t < nb) ? bsums[t] : 0;
    int x = v;
#pragma unroll
    for (int d = 1; d < 64; d <<= 1) { int y = __shfl_up(x, d, 64); if (lane >= d) x += y; }
    if (lane == 63) wsum[w] = x;
    __syncthreads();
    int pre = (w == 1) ? wsum[0] : 0;
    if (t < nb) bsums[t] = x - v + pre;
}

__global__ __launch_bounds__(256) void scan3_kernel(int* __restrict__ offsets,
                                                    const int* __restrict__ bsums, int N) {
    int i = blockIdx.x * 256 + threadIdx.x;
    if (i < N) offsets[i] += bsums[i >> 10];
}

// bucket: after this, offsets[d] = END of bucket d
__global__ __launch_bounds__(256) void bucket_kernel(const int* __restrict__ src,
                                                     const int* __restrict__ dst,
                                                     int* __restrict__ offsets,
                                                     int* __restrict__ edge_src, int E) {
    int e = blockIdx.x * 256 + threadIdx.x;
    if (e < E) {
        int pos = atomicAdd(&offsets[dst[e]], 1);
        edge_src[pos] = src[e];
    }
}

// ---------------- Gather (bf16 proj): one wave per node ----------------
__global__ __launch_bounds__(256) void gather_kernel(const unsigned short* __restrict__ projb,
                                                     const int* __restrict__ edge_src,
                                                     const int* __restrict__ offsets,
                                                     const int* __restrict__ counts,
                                                     float* __restrict__ out, int N) {
    const int node = blockIdx.x * 4 + (threadIdx.x >> 6);
    const int lane = threadIdx.x & 63;
    if (node >= N) return;

    const int end = offsets[node];
    const int beg = end - counts[node];

    float ax = 0.f, ay = 0.f;
    int e = beg;
    for (; e + 3 < end; e += 4) {
        int s0 = edge_src[e], s1 = edge_src[e + 1], s2 = edge_src[e + 2], s3 = edge_src[e + 3];
        unsigned int v0 = *(const unsigned int*)&projb[(size_t)s0 * OUT_DIM + lane * 2];
        unsigned int v1 = *(const unsigned int*)&projb[(size_t)s1 * OUT_DIM + lane * 2];
        unsigned int v2 = *(const unsigned int*)&projb[(size_t)s2 * OUT_DIM + lane * 2];
        unsigned int v3 = *(const unsigned int*)&projb[(size_t)s3 * OUT_DIM + lane * 2];
        ax += (bf_lo(v0) + bf_lo(v1)) + (bf_lo(v2) + bf_lo(v3));
        ay += (bf_hi(v0) + bf_hi(v1)) + (bf_hi(v2) + bf_hi(v3));
    }
    for (; e < end; e++) {
        unsigned int v = *(const unsigned int*)&projb[(size_t)edge_src[e] * OUT_DIM + lane * 2];
        ax += bf_lo(v);
        ay += bf_hi(v);
    }
    *(float2*)&out[(size_t)node * OUT_DIM + lane * 2] = make_float2(ax, ay);
}

extern "C" void kernel_launch(void* const* d_in, const int* in_sizes, int n_in,
                              void* d_out, int out_size, void* d_ws, size_t ws_size,
                              hipStream_t stream) {
    const float* h   = (const float*)d_in[0];
    const float* W   = (const float*)d_in[1];
    const int*   src = (const int*)d_in[2];
    const int*   dst = (const int*)d_in[3];
    float* out = (float*)d_out;

    const int M = in_sizes[0] / IN_DIM;
    const int E = in_sizes[2];

    char* ws = (char*)d_ws;
    unsigned short* projb = (unsigned short*)ws;                 // M*128 bf16 = 25.6 MB
    size_t off = (size_t)M * OUT_DIM * sizeof(unsigned short);
    off = (off + 255) & ~(size_t)255;
    int* counts   = (int*)(ws + off); off += (size_t)M * sizeof(int);
    int* offsets  = (int*)(ws + off); off += (size_t)M * sizeof(int);
    int* bsums    = (int*)(ws + off); off += 1024 * sizeof(int);
    int* edge_src = (int*)(ws + off); off += (size_t)E * sizeof(int);

    // 1) projection + relu (bf16 MFMA)
    proj_mfma_kernel<<<(M + 63) / 64, 256, 0, stream>>>(h, W, projb, M);

    // 2) CSR build
    hipMemsetAsync(counts, 0, (size_t)M * sizeof(int), stream);
    hist_kernel<<<(E + 255) / 256, 256, 0, stream>>>(dst, counts, E);
    const int nb = (M + 1023) / 1024;   // must be <= 128
    scan1_kernel<<<nb, 1024, 0, stream>>>(counts, offsets, bsums, M);
    scan2_kernel<<<1, 128, 0, stream>>>(bsums, nb);
    scan3_kernel<<<(M + 255) / 256, 256, 0, stream>>>(offsets, bsums, M);
    bucket_kernel<<<(E + 255) / 256, 256, 0, stream>>>(src, dst, offsets, edge_src, E);

    // 3) pull-gather
    gather_kernel<<<(M + 3) / 4, 256, 0, stream>>>(projb, edge_src, offsets, counts, out, M);
}